// Round 1
// baseline (1601.007 us; speedup 1.0000x reference)
//
#include <hip/hip_runtime.h>
#include <math.h>

#define NN      65536
#define NE      1048576
#define NPER    1024
#define NGRAPH  64
#define KPER    512
#define IND     192
#define PED     64
#define HID     256
#define LAT     128

// workspace offsets (4-byte elements)
#define OFF_CNT     0u          // 65536 int
#define OFF_ROWPTR  65536u      // 65537 int
#define OFF_CUR     132096u     // 65536 int
#define OFF_DINV    198656u     // 65536 f
#define OFF_ESRC    264192u     // 1048576 int
#define OFF_ENORM   1312768u    // 1048576 f
#define OFF_INVWN   2361344u    // 1 f
#define OFF_KEEP    2361360u    // 32768 int
#define OFF_SCORE   2395136u    // 65536 f
#define OFF_T0      2460672u    // 16777216 f  (t0, reused as t1)
#define OFF_H       19237888u   // 16777216 f  (h, reused as mu|lv)
#define OFF_MU      19237888u
#define OFF_LV      27626496u

// d_out offsets (floats)
#define OUT_MU      4194304
#define OUT_LV      8388608
#define OUT_BATCH   12582912
#define OUT_PERM    12615680

__global__ __launch_bounds__(256) void k_count(const int* __restrict__ ei, int* __restrict__ cnt) {
    int e = blockIdx.x * 256 + threadIdx.x;
    atomicAdd(&cnt[ei[NE + e]], 1);
}

__global__ __launch_bounds__(1024) void k_scan(const int* __restrict__ cnt, int* __restrict__ rp,
                                               float* __restrict__ dinv) {
    __shared__ int part[1024];
    const int t = threadIdx.x;
    const int base = t * 64;
    int s = 0;
    for (int i = 0; i < 64; ++i) s += cnt[base + i];
    part[t] = s;
    __syncthreads();
    for (int d = 1; d < 1024; d <<= 1) {
        int v = (t >= d) ? part[t - d] : 0;
        __syncthreads();
        part[t] += v;
        __syncthreads();
    }
    int run = part[t] - s;   // exclusive prefix over threads
    for (int i = 0; i < 64; ++i) {
        int c = cnt[base + i];
        rp[base + i] = run;
        run += c;
        dinv[base + i] = 1.0f / sqrtf((float)(c + 1));  // +1 self loop
    }
    if (t == 1023) rp[NN] = run;
}

__global__ __launch_bounds__(256) void k_scatter(const int* __restrict__ ei, const int* __restrict__ rp,
                                                 int* __restrict__ cur, const float* __restrict__ dinv,
                                                 int* __restrict__ esrc, float* __restrict__ enorm) {
    int e = blockIdx.x * 256 + threadIdx.x;
    int s = ei[e];
    int d = ei[NE + e];
    int pos = rp[d] + atomicAdd(&cur[d], 1);
    esrc[pos] = s;
    enorm[pos] = dinv[s] * dinv[d];
}

__global__ __launch_bounds__(128) void k_wnorm(const float* __restrict__ wp, float* __restrict__ invwn) {
    __shared__ float red[128];
    int t = threadIdx.x;
    float v = wp[t];
    red[t] = v * v;
    __syncthreads();
    for (int s = 64; s > 0; s >>= 1) {
        if (t < s) red[t] += red[t + s];
        __syncthreads();
    }
    if (t == 0) invwn[0] = 1.0f / sqrtf(red[0]);
}

// GEMM: C[N,256] = A[N,256] @ B[256,256]
// MODE 0: A = concat(x_raw[.,192], pe[.,64]); B = W1 [256x256]
// MODE 1: A = h [N,256]; B = concat cols (Wmu [256x128] | Wlv [256x128])
// block: 256 thr = 4 waves; block handles 64 rows; blockIdx.y = col-group of 64.
// lane = column within group; each wave computes 16 rows x 64 cols.
template <int MODE>
__global__ __launch_bounds__(256) void k_gemm(const float* __restrict__ A0, const float* __restrict__ A1,
                                              const float* __restrict__ B0, const float* __restrict__ B1,
                                              float* __restrict__ C) {
    __shared__ float Blds[256 * 68];
    const int tid  = threadIdx.x;
    const int lane = tid & 63;
    const int w    = __builtin_amdgcn_readfirstlane(tid >> 6);
    const int cg   = blockIdx.y;

    // stage B[:, cg*64 .. +64) into LDS
    {
        const float* Bp;
        int ldb, cb;
        if (MODE == 0) { Bp = B0; ldb = 256; cb = cg * 64; }
        else           { Bp = (cg < 2) ? B0 : B1; ldb = 128; cb = (cg & 1) * 64; }
        const int c4 = (tid & 15) * 4;
        const int kb = tid >> 4;
        for (int i = 0; i < 16; ++i) {
            int k = kb + i * 16;
            float4 v = *(const float4*)(Bp + k * ldb + cb + c4);
            *(float4*)(&Blds[k * 68 + c4]) = v;
        }
    }
    __syncthreads();

    const int r0 = blockIdx.x * 64 + w * 16;
    float acc[16];
#pragma unroll
    for (int i = 0; i < 16; ++i) acc[i] = 0.0f;

    if (MODE == 0) {
#pragma unroll 2
        for (int k0 = 0; k0 < 192; k0 += 4) {
            float b0 = Blds[(k0 + 0) * 68 + lane];
            float b1 = Blds[(k0 + 1) * 68 + lane];
            float b2 = Blds[(k0 + 2) * 68 + lane];
            float b3 = Blds[(k0 + 3) * 68 + lane];
#pragma unroll
            for (int i = 0; i < 16; ++i) {
                float4 a = *(const float4*)(A0 + (r0 + i) * IND + k0);
                acc[i] = fmaf(a.x, b0, fmaf(a.y, b1, fmaf(a.z, b2, fmaf(a.w, b3, acc[i]))));
            }
        }
#pragma unroll 2
        for (int k0 = 0; k0 < 64; k0 += 4) {
            float b0 = Blds[(k0 + 192) * 68 + lane];
            float b1 = Blds[(k0 + 193) * 68 + lane];
            float b2 = Blds[(k0 + 194) * 68 + lane];
            float b3 = Blds[(k0 + 195) * 68 + lane];
#pragma unroll
            for (int i = 0; i < 16; ++i) {
                float4 a = *(const float4*)(A1 + (r0 + i) * PED + k0);
                acc[i] = fmaf(a.x, b0, fmaf(a.y, b1, fmaf(a.z, b2, fmaf(a.w, b3, acc[i]))));
            }
        }
    } else {
#pragma unroll 2
        for (int k0 = 0; k0 < 256; k0 += 4) {
            float b0 = Blds[(k0 + 0) * 68 + lane];
            float b1 = Blds[(k0 + 1) * 68 + lane];
            float b2 = Blds[(k0 + 2) * 68 + lane];
            float b3 = Blds[(k0 + 3) * 68 + lane];
#pragma unroll
            for (int i = 0; i < 16; ++i) {
                float4 a = *(const float4*)(A0 + (r0 + i) * 256 + k0);
                acc[i] = fmaf(a.x, b0, fmaf(a.y, b1, fmaf(a.z, b2, fmaf(a.w, b3, acc[i]))));
            }
        }
    }

    const int cbase = cg * 64 + lane;
#pragma unroll
    for (int i = 0; i < 16; ++i) C[(r0 + i) * 256 + cbase] = acc[i];
}

// aggregation 1: h = relu(sum_{in-edges} norm * t0[src] + dinv^2 * t0[node] + b1)
__global__ __launch_bounds__(256) void k_agg1(const float* __restrict__ t0, const int* __restrict__ rp,
                                              const int* __restrict__ esrc, const float* __restrict__ enorm,
                                              const float* __restrict__ dinv, const float* __restrict__ bias,
                                              float* __restrict__ hout) {
    const int wv = threadIdx.x >> 6, lane = threadIdx.x & 63;
    const int node = blockIdx.x * 4 + wv;
    const int c0 = lane * 4;
    const float di = dinv[node];
    float4 acc = *(const float4*)(t0 + (size_t)node * 256 + c0);
    const float sw = di * di;
    acc.x *= sw; acc.y *= sw; acc.z *= sw; acc.w *= sw;
    const int beg = rp[node], end = rp[node + 1];
    for (int e = beg; e < end; ++e) {
        const int s = esrc[e];
        const float wgt = enorm[e];
        const float4 v = *(const float4*)(t0 + (size_t)s * 256 + c0);
        acc.x = fmaf(wgt, v.x, acc.x);
        acc.y = fmaf(wgt, v.y, acc.y);
        acc.z = fmaf(wgt, v.z, acc.z);
        acc.w = fmaf(wgt, v.w, acc.w);
    }
    const float4 bb = *(const float4*)(bias + c0);
    float4 r;
    r.x = fmaxf(acc.x + bb.x, 0.0f);
    r.y = fmaxf(acc.y + bb.y, 0.0f);
    r.z = fmaxf(acc.z + bb.z, 0.0f);
    r.w = fmaxf(acc.w + bb.w, 0.0f);
    *(float4*)(hout + (size_t)node * 256 + c0) = r;
}

// aggregation 2: t1 cols 0..127 -> mu, 128..255 -> lv; also z & score
__global__ __launch_bounds__(256) void k_agg2(const float* __restrict__ t1, const int* __restrict__ rp,
                                              const int* __restrict__ esrc, const float* __restrict__ enorm,
                                              const float* __restrict__ dinv, const float* __restrict__ bmu,
                                              const float* __restrict__ blv, const float* __restrict__ eps,
                                              const float* __restrict__ wp, const float* __restrict__ invwn,
                                              float* __restrict__ mu, float* __restrict__ lv,
                                              float* __restrict__ score) {
    const int wv = threadIdx.x >> 6, lane = threadIdx.x & 63;
    const int node = blockIdx.x * 4 + wv;
    const int c0 = lane * 4;
    const float di = dinv[node];
    float4 acc = *(const float4*)(t1 + (size_t)node * 256 + c0);
    const float sw = di * di;
    acc.x *= sw; acc.y *= sw; acc.z *= sw; acc.w *= sw;
    const int beg = rp[node], end = rp[node + 1];
    for (int e = beg; e < end; ++e) {
        const int s = esrc[e];
        const float wgt = enorm[e];
        const float4 v = *(const float4*)(t1 + (size_t)s * 256 + c0);
        acc.x = fmaf(wgt, v.x, acc.x);
        acc.y = fmaf(wgt, v.y, acc.y);
        acc.z = fmaf(wgt, v.z, acc.z);
        acc.w = fmaf(wgt, v.w, acc.w);
    }
    const int cb = (lane & 31) * 4;
    const float* bias = (lane < 32) ? bmu : blv;
    const float4 bb = *(const float4*)(bias + cb);
    acc.x += bb.x; acc.y += bb.y; acc.z += bb.z; acc.w += bb.w;
    if (lane < 32) *(float4*)(mu + (size_t)node * 128 + cb) = acc;
    else           *(float4*)(lv + (size_t)node * 128 + cb) = acc;
    // z = mu + eps*exp(0.5*lv); partial dot with w_pool (lanes 0..31 hold mu cols)
    float4 l4;
    l4.x = __shfl(acc.x, lane | 32, 64);
    l4.y = __shfl(acc.y, lane | 32, 64);
    l4.z = __shfl(acc.z, lane | 32, 64);
    l4.w = __shfl(acc.w, lane | 32, 64);
    float partial = 0.0f;
    if (lane < 32) {
        const float4 e4 = *(const float4*)(eps + (size_t)node * 128 + cb);
        const float4 w4 = *(const float4*)(wp + cb);
        float zx = fmaf(e4.x, expf(0.5f * l4.x), acc.x);
        float zy = fmaf(e4.y, expf(0.5f * l4.y), acc.y);
        float zz = fmaf(e4.z, expf(0.5f * l4.z), acc.z);
        float zw = fmaf(e4.w, expf(0.5f * l4.w), acc.w);
        partial = zx * w4.x + zy * w4.y + zz * w4.z + zw * w4.w;
    }
    for (int off = 16; off > 0; off >>= 1) partial += __shfl_xor(partial, off, 64);
    if (lane == 0) score[node] = tanhf(partial * invwn[0]);
}

// per-graph bitonic top-k: sort 1024 (score desc, idx asc), emit top 512
__global__ __launch_bounds__(512) void k_topk(const float* __restrict__ score, const int* __restrict__ batch,
                                              int* __restrict__ keep, float* __restrict__ out) {
    __shared__ float sk[1024];
    __shared__ int si[1024];
    const int g = blockIdx.x, t = threadIdx.x;
    for (int i = t; i < 1024; i += 512) {
        sk[i] = score[g * 1024 + i];
        si[i] = i;
    }
    __syncthreads();
    for (int k = 2; k <= 1024; k <<= 1) {
        for (int j = k >> 1; j > 0; j >>= 1) {
            for (int base = 0; base < 1024; base += 512) {
                int i = base + t;
                int ixj = i ^ j;
                if (ixj > i) {
                    float a = sk[i], b = sk[ixj];
                    int ia = si[i], ib = si[ixj];
                    bool before = (a > b) || (a == b && ia < ib);
                    bool up = ((i & k) == 0);
                    bool sw = up ? (!before) : before;
                    if (sw) {
                        sk[i] = b; si[i] = ib;
                        sk[ixj] = a; si[ixj] = ia;
                    }
                }
            }
            __syncthreads();
        }
    }
    if (t < KPER) {
        int node = g * 1024 + si[t];
        keep[g * KPER + t] = node;
        out[OUT_BATCH + g * KPER + t] = (float)batch[node];
        out[OUT_PERM + g * KPER + t] = (float)node;
    }
}

__global__ __launch_bounds__(128) void k_gather(const int* __restrict__ keep, const float* __restrict__ mu,
                                                const float* __restrict__ lv, const float* __restrict__ eps,
                                                const float* __restrict__ score, float* __restrict__ out) {
    const int kidx = blockIdx.x;
    const int c = threadIdx.x;
    const int node = keep[kidx];
    const float m = mu[(size_t)node * 128 + c];
    const float l = lv[(size_t)node * 128 + c];
    const float e = eps[(size_t)node * 128 + c];
    const float z = fmaf(e, expf(0.5f * l), m);
    const float s = score[node];
    out[(size_t)kidx * 128 + c] = z * s;
    out[OUT_MU + (size_t)kidx * 128 + c] = m;
    out[OUT_LV + (size_t)kidx * 128 + c] = l;
}

extern "C" void kernel_launch(void* const* d_in, const int* in_sizes, int n_in,
                              void* d_out, int out_size, void* d_ws, size_t ws_size,
                              hipStream_t stream) {
    (void)in_sizes; (void)n_in; (void)out_size; (void)ws_size;
    const float* x_raw = (const float*)d_in[0];
    const float* pe    = (const float*)d_in[1];
    const int*   ei    = (const int*)d_in[2];
    const int*   batch = (const int*)d_in[3];
    const float* eps   = (const float*)d_in[4];
    const float* W1    = (const float*)d_in[5];
    const float* b1    = (const float*)d_in[6];
    const float* Wmu   = (const float*)d_in[7];
    const float* bmu   = (const float*)d_in[8];
    const float* Wlv   = (const float*)d_in[9];
    const float* blv   = (const float*)d_in[10];
    const float* wp    = (const float*)d_in[11];
    float* ws = (float*)d_ws;
    int*  iws = (int*)d_ws;
    float* out = (float*)d_out;

    hipMemsetAsync(iws + OFF_CNT, 0, 65536 * 4, stream);
    hipMemsetAsync(iws + OFF_CUR, 0, 65536 * 4, stream);

    k_count<<<NE / 256, 256, 0, stream>>>(ei, iws + OFF_CNT);
    k_scan<<<1, 1024, 0, stream>>>(iws + OFF_CNT, iws + OFF_ROWPTR, ws + OFF_DINV);
    k_scatter<<<NE / 256, 256, 0, stream>>>(ei, iws + OFF_ROWPTR, iws + OFF_CUR, ws + OFF_DINV,
                                            iws + OFF_ESRC, ws + OFF_ENORM);
    k_wnorm<<<1, 128, 0, stream>>>(wp, ws + OFF_INVWN);

    k_gemm<0><<<dim3(NN / 64, 4), 256, 0, stream>>>(x_raw, pe, W1, nullptr, ws + OFF_T0);
    k_agg1<<<NN / 4, 256, 0, stream>>>(ws + OFF_T0, iws + OFF_ROWPTR, iws + OFF_ESRC, ws + OFF_ENORM,
                                       ws + OFF_DINV, b1, ws + OFF_H);
    k_gemm<1><<<dim3(NN / 64, 4), 256, 0, stream>>>(ws + OFF_H, nullptr, Wmu, Wlv, ws + OFF_T0);
    k_agg2<<<NN / 4, 256, 0, stream>>>(ws + OFF_T0, iws + OFF_ROWPTR, iws + OFF_ESRC, ws + OFF_ENORM,
                                       ws + OFF_DINV, bmu, blv, eps, wp, ws + OFF_INVWN,
                                       ws + OFF_MU, ws + OFF_LV, ws + OFF_SCORE);
    k_topk<<<NGRAPH, 512, 0, stream>>>(ws + OFF_SCORE, batch, iws + OFF_KEEP, out);
    k_gather<<<NGRAPH * KPER, 128, 0, stream>>>(iws + OFF_KEEP, ws + OFF_MU, ws + OFF_LV, eps,
                                                ws + OFF_SCORE, out);
}

// Round 2
// 990.384 us; speedup vs baseline: 1.6166x; 1.6166x over previous
//
#include <hip/hip_runtime.h>
#include <math.h>

#define NN      65536
#define NE      1048576
#define NPER    1024
#define NGRAPH  64
#define KPER    512
#define IND     192
#define PED     64
#define HID     256
#define LAT     128

// workspace offsets (4-byte elements)
#define OFF_CNT     0u          // 65536 int
#define OFF_ROWPTR  65536u      // 65537 int
#define OFF_CUR     132096u     // 65536 int
#define OFF_DINV    198656u     // 65536 f
#define OFF_ESRC    264192u     // 1048576 int
#define OFF_ENORM   1312768u    // 1048576 f
#define OFF_INVWN   2361344u    // 1 f
#define OFF_KEEP    2361360u    // 32768 int
#define OFF_SCORE   2395136u    // 65536 f
#define OFF_T0      2460672u    // 16777216 f  (t0, reused as t1)
#define OFF_H       19237888u   // 16777216 f  (h, reused as mu|lv)
#define OFF_MU      19237888u
#define OFF_LV      27626496u

// d_out offsets (floats)
#define OUT_MU      4194304
#define OUT_LV      8388608
#define OUT_BATCH   12582912
#define OUT_PERM    12615680

__global__ __launch_bounds__(256) void k_count(const int* __restrict__ ei, int* __restrict__ cnt) {
    int e = blockIdx.x * 256 + threadIdx.x;
    atomicAdd(&cnt[ei[NE + e]], 1);
}

__global__ __launch_bounds__(1024) void k_scan(const int* __restrict__ cnt, int* __restrict__ rp,
                                               float* __restrict__ dinv) {
    __shared__ int part[1024];
    const int t = threadIdx.x;
    const int base = t * 64;
    int s = 0;
    for (int i = 0; i < 64; ++i) s += cnt[base + i];
    part[t] = s;
    __syncthreads();
    for (int d = 1; d < 1024; d <<= 1) {
        int v = (t >= d) ? part[t - d] : 0;
        __syncthreads();
        part[t] += v;
        __syncthreads();
    }
    int run = part[t] - s;   // exclusive prefix over threads
    for (int i = 0; i < 64; ++i) {
        int c = cnt[base + i];
        rp[base + i] = run;
        run += c;
        dinv[base + i] = 1.0f / sqrtf((float)(c + 1));  // +1 self loop
    }
    if (t == 1023) rp[NN] = run;
}

__global__ __launch_bounds__(256) void k_scatter(const int* __restrict__ ei, const int* __restrict__ rp,
                                                 int* __restrict__ cur, const float* __restrict__ dinv,
                                                 int* __restrict__ esrc, float* __restrict__ enorm) {
    int e = blockIdx.x * 256 + threadIdx.x;
    int s = ei[e];
    int d = ei[NE + e];
    int pos = rp[d] + atomicAdd(&cur[d], 1);
    esrc[pos] = s;
    enorm[pos] = dinv[s] * dinv[d];
}

__global__ __launch_bounds__(128) void k_wnorm(const float* __restrict__ wp, float* __restrict__ invwn) {
    __shared__ float red[128];
    int t = threadIdx.x;
    float v = wp[t];
    red[t] = v * v;
    __syncthreads();
    for (int s = 64; s > 0; s >>= 1) {
        if (t < s) red[t] += red[t + s];
        __syncthreads();
    }
    if (t == 0) invwn[0] = 1.0f / sqrtf(red[0]);
}

#define FMA4(d, a, b) \
    d.x = fmaf(a, b.x, d.x); d.y = fmaf(a, b.y, d.y); \
    d.z = fmaf(a, b.z, d.z); d.w = fmaf(a, b.w, d.w)

// Register-blocked SGEMM: C[N,256] = A[N,256] @ B[256,256]
// Block tile M=128 x N=256 (all cols -> A fetched exactly once), BK=16, 16 stages.
// 256 threads; micro-tile 8 rows x 16 cols per thread; A in LDS transposed (pad 132),
// B in LDS row-major; register prefetch pipeline across stages.
// MODE 0: A = [x_raw(192) | pe(64)], B = W1[256x256]
// MODE 1: A = h[N,256],  B = [Wmu(256x128) | Wlv(256x128)] col-concat
template <int MODE>
__global__ __launch_bounds__(256, 2) void k_gemm(const float* __restrict__ A0, const float* __restrict__ A1,
                                                 const float* __restrict__ B0, const float* __restrict__ B1,
                                                 float* __restrict__ C) {
    __shared__ float Alds[16 * 132];
    __shared__ float Blds[16 * 256];
    const int tid = threadIdx.x;
    const int tx = tid & 15;     // col group: cols tx*4 + {0,64,128,192}
    const int ty = tid >> 4;     // row group: rows ty*8 .. ty*8+7
    const int Rbase = blockIdx.x * 128;

    // staging indices
    const int rowA = tid >> 2;        // 0..63
    const int c4   = (tid & 3) * 4;   // 0,4,8,12
    const int krB  = tid >> 4;        // 0..15
    const int cbB  = (tid & 15) * 4;  // 0..60

    float4 pa0, pa1, pb0, pb1, pb2, pb3;

    auto loadA = [&](int s, float4& v0, float4& v1) {
        const float* p; int ld, ko;
        if (MODE == 0) {
            if (s < 12) { p = A0; ld = IND; ko = s * 16; }
            else        { p = A1; ld = PED; ko = s * 16 - IND; }
        } else { p = A0; ld = 256; ko = s * 16; }
        v0 = *(const float4*)(p + (size_t)(Rbase + rowA) * ld + ko + c4);
        v1 = *(const float4*)(p + (size_t)(Rbase + rowA + 64) * ld + ko + c4);
    };
    auto loadB = [&](int s, float4& b0, float4& b1, float4& b2, float4& b3) {
        const int k = s * 16 + krB;
        if (MODE == 0) {
            const float* p = B0 + (size_t)k * 256;
            b0 = *(const float4*)(p + cbB);
            b1 = *(const float4*)(p + cbB + 64);
            b2 = *(const float4*)(p + cbB + 128);
            b3 = *(const float4*)(p + cbB + 192);
        } else {
            const float* pm = B0 + (size_t)k * 128;
            const float* pl = B1 + (size_t)k * 128;
            b0 = *(const float4*)(pm + cbB);
            b1 = *(const float4*)(pm + cbB + 64);
            b2 = *(const float4*)(pl + cbB);
            b3 = *(const float4*)(pl + cbB + 64);
        }
    };

    float4 acc[8][4];
#pragma unroll
    for (int r = 0; r < 8; ++r)
#pragma unroll
        for (int i = 0; i < 4; ++i) acc[r][i] = make_float4(0.f, 0.f, 0.f, 0.f);

    loadA(0, pa0, pa1);
    loadB(0, pb0, pb1, pb2, pb3);

    for (int s = 0; s < 16; ++s) {
#pragma unroll
        for (int j = 0; j < 4; ++j) {
            Alds[(c4 + j) * 132 + rowA]      = ((const float*)&pa0)[j];
            Alds[(c4 + j) * 132 + rowA + 64] = ((const float*)&pa1)[j];
        }
        *(float4*)&Blds[krB * 256 + cbB]       = pb0;
        *(float4*)&Blds[krB * 256 + cbB + 64]  = pb1;
        *(float4*)&Blds[krB * 256 + cbB + 128] = pb2;
        *(float4*)&Blds[krB * 256 + cbB + 192] = pb3;
        __syncthreads();
        if (s < 15) { loadA(s + 1, pa0, pa1); loadB(s + 1, pb0, pb1, pb2, pb3); }
#pragma unroll
        for (int k = 0; k < 16; ++k) {
            const float4 a0 = *(const float4*)&Alds[k * 132 + ty * 8];
            const float4 a1 = *(const float4*)&Alds[k * 132 + ty * 8 + 4];
            const float4 b0 = *(const float4*)&Blds[k * 256 + tx * 4];
            const float4 b1 = *(const float4*)&Blds[k * 256 + tx * 4 + 64];
            const float4 b2 = *(const float4*)&Blds[k * 256 + tx * 4 + 128];
            const float4 b3 = *(const float4*)&Blds[k * 256 + tx * 4 + 192];
            const float ar[8] = {a0.x, a0.y, a0.z, a0.w, a1.x, a1.y, a1.z, a1.w};
#pragma unroll
            for (int r = 0; r < 8; ++r) {
                FMA4(acc[r][0], ar[r], b0);
                FMA4(acc[r][1], ar[r], b1);
                FMA4(acc[r][2], ar[r], b2);
                FMA4(acc[r][3], ar[r], b3);
            }
        }
        __syncthreads();
    }

#pragma unroll
    for (int r = 0; r < 8; ++r) {
        const int row = Rbase + ty * 8 + r;
#pragma unroll
        for (int i = 0; i < 4; ++i)
            *(float4*)(C + (size_t)row * 256 + tx * 4 + i * 64) = acc[r][i];
    }
}

// aggregation 1: h = relu(sum_{in-edges} norm * t0[src] + dinv^2 * t0[node] + b1)
// wave per node; edges processed in coalesced 64-wide chunks broadcast via shfl.
__global__ __launch_bounds__(256) void k_agg1(const float* __restrict__ t0, const int* __restrict__ rp,
                                              const int* __restrict__ esrc, const float* __restrict__ enorm,
                                              const float* __restrict__ dinv, const float* __restrict__ bias,
                                              float* __restrict__ hout) {
    const int wv = threadIdx.x >> 6, lane = threadIdx.x & 63;
    const int node = blockIdx.x * 4 + wv;
    const int c0 = lane * 4;
    const float di = dinv[node];
    float4 acc = *(const float4*)(t0 + (size_t)node * 256 + c0);
    const float sw = di * di;
    acc.x *= sw; acc.y *= sw; acc.z *= sw; acc.w *= sw;
    const int beg = rp[node], end = rp[node + 1];
    for (int base = beg; base < end; base += 64) {
        const int m = min(64, end - base);
        int sv = 0; float nv = 0.0f;
        if (lane < m) { sv = esrc[base + lane]; nv = enorm[base + lane]; }
        float4 vj = *(const float4*)(t0 + (size_t)__shfl(sv, 0, 64) * 256 + c0);
        for (int j = 0; j < m; ++j) {
            const float wgt = __shfl(nv, j, 64);
            float4 vnext;
            if (j + 1 < m) vnext = *(const float4*)(t0 + (size_t)__shfl(sv, j + 1, 64) * 256 + c0);
            acc.x = fmaf(wgt, vj.x, acc.x);
            acc.y = fmaf(wgt, vj.y, acc.y);
            acc.z = fmaf(wgt, vj.z, acc.z);
            acc.w = fmaf(wgt, vj.w, acc.w);
            vj = vnext;
        }
    }
    const float4 bb = *(const float4*)(bias + c0);
    float4 r;
    r.x = fmaxf(acc.x + bb.x, 0.0f);
    r.y = fmaxf(acc.y + bb.y, 0.0f);
    r.z = fmaxf(acc.z + bb.z, 0.0f);
    r.w = fmaxf(acc.w + bb.w, 0.0f);
    *(float4*)(hout + (size_t)node * 256 + c0) = r;
}

// aggregation 2: t1 cols 0..127 -> mu, 128..255 -> lv; also z & score
__global__ __launch_bounds__(256) void k_agg2(const float* __restrict__ t1, const int* __restrict__ rp,
                                              const int* __restrict__ esrc, const float* __restrict__ enorm,
                                              const float* __restrict__ dinv, const float* __restrict__ bmu,
                                              const float* __restrict__ blv, const float* __restrict__ eps,
                                              const float* __restrict__ wp, const float* __restrict__ invwn,
                                              float* __restrict__ mu, float* __restrict__ lv,
                                              float* __restrict__ score) {
    const int wv = threadIdx.x >> 6, lane = threadIdx.x & 63;
    const int node = blockIdx.x * 4 + wv;
    const int c0 = lane * 4;
    const float di = dinv[node];
    float4 acc = *(const float4*)(t1 + (size_t)node * 256 + c0);
    const float sw = di * di;
    acc.x *= sw; acc.y *= sw; acc.z *= sw; acc.w *= sw;
    const int beg = rp[node], end = rp[node + 1];
    for (int base = beg; base < end; base += 64) {
        const int m = min(64, end - base);
        int sv = 0; float nv = 0.0f;
        if (lane < m) { sv = esrc[base + lane]; nv = enorm[base + lane]; }
        float4 vj = *(const float4*)(t1 + (size_t)__shfl(sv, 0, 64) * 256 + c0);
        for (int j = 0; j < m; ++j) {
            const float wgt = __shfl(nv, j, 64);
            float4 vnext;
            if (j + 1 < m) vnext = *(const float4*)(t1 + (size_t)__shfl(sv, j + 1, 64) * 256 + c0);
            acc.x = fmaf(wgt, vj.x, acc.x);
            acc.y = fmaf(wgt, vj.y, acc.y);
            acc.z = fmaf(wgt, vj.z, acc.z);
            acc.w = fmaf(wgt, vj.w, acc.w);
            vj = vnext;
        }
    }
    const int cb = (lane & 31) * 4;
    const float* bias = (lane < 32) ? bmu : blv;
    const float4 bb = *(const float4*)(bias + cb);
    acc.x += bb.x; acc.y += bb.y; acc.z += bb.z; acc.w += bb.w;
    if (lane < 32) *(float4*)(mu + (size_t)node * 128 + cb) = acc;
    else           *(float4*)(lv + (size_t)node * 128 + cb) = acc;
    // z = mu + eps*exp(0.5*lv); partial dot with w_pool (lanes 0..31 hold mu cols)
    float4 l4;
    l4.x = __shfl(acc.x, lane | 32, 64);
    l4.y = __shfl(acc.y, lane | 32, 64);
    l4.z = __shfl(acc.z, lane | 32, 64);
    l4.w = __shfl(acc.w, lane | 32, 64);
    float partial = 0.0f;
    if (lane < 32) {
        const float4 e4 = *(const float4*)(eps + (size_t)node * 128 + cb);
        const float4 w4 = *(const float4*)(wp + cb);
        float zx = fmaf(e4.x, expf(0.5f * l4.x), acc.x);
        float zy = fmaf(e4.y, expf(0.5f * l4.y), acc.y);
        float zz = fmaf(e4.z, expf(0.5f * l4.z), acc.z);
        float zw = fmaf(e4.w, expf(0.5f * l4.w), acc.w);
        partial = zx * w4.x + zy * w4.y + zz * w4.z + zw * w4.w;
    }
    for (int off = 16; off > 0; off >>= 1) partial += __shfl_xor(partial, off, 64);
    if (lane == 0) score[node] = tanhf(partial * invwn[0]);
}

// per-graph bitonic top-k: sort 1024 (score desc, idx asc), emit top 512
__global__ __launch_bounds__(512) void k_topk(const float* __restrict__ score, const int* __restrict__ batch,
                                              int* __restrict__ keep, float* __restrict__ out) {
    __shared__ float sk[1024];
    __shared__ int si[1024];
    const int g = blockIdx.x, t = threadIdx.x;
    for (int i = t; i < 1024; i += 512) {
        sk[i] = score[g * 1024 + i];
        si[i] = i;
    }
    __syncthreads();
    for (int k = 2; k <= 1024; k <<= 1) {
        for (int j = k >> 1; j > 0; j >>= 1) {
            for (int base = 0; base < 1024; base += 512) {
                int i = base + t;
                int ixj = i ^ j;
                if (ixj > i) {
                    float a = sk[i], b = sk[ixj];
                    int ia = si[i], ib = si[ixj];
                    bool before = (a > b) || (a == b && ia < ib);
                    bool up = ((i & k) == 0);
                    bool sw = up ? (!before) : before;
                    if (sw) {
                        sk[i] = b; si[i] = ib;
                        sk[ixj] = a; si[ixj] = ia;
                    }
                }
            }
            __syncthreads();
        }
    }
    if (t < KPER) {
        int node = g * 1024 + si[t];
        keep[g * KPER + t] = node;
        out[OUT_BATCH + g * KPER + t] = (float)batch[node];
        out[OUT_PERM + g * KPER + t] = (float)node;
    }
}

__global__ __launch_bounds__(128) void k_gather(const int* __restrict__ keep, const float* __restrict__ mu,
                                                const float* __restrict__ lv, const float* __restrict__ eps,
                                                const float* __restrict__ score, float* __restrict__ out) {
    const int kidx = blockIdx.x;
    const int c = threadIdx.x;
    const int node = keep[kidx];
    const float m = mu[(size_t)node * 128 + c];
    const float l = lv[(size_t)node * 128 + c];
    const float e = eps[(size_t)node * 128 + c];
    const float z = fmaf(e, expf(0.5f * l), m);
    const float s = score[node];
    out[(size_t)kidx * 128 + c] = z * s;
    out[OUT_MU + (size_t)kidx * 128 + c] = m;
    out[OUT_LV + (size_t)kidx * 128 + c] = l;
}

extern "C" void kernel_launch(void* const* d_in, const int* in_sizes, int n_in,
                              void* d_out, int out_size, void* d_ws, size_t ws_size,
                              hipStream_t stream) {
    (void)in_sizes; (void)n_in; (void)out_size; (void)ws_size;
    const float* x_raw = (const float*)d_in[0];
    const float* pe    = (const float*)d_in[1];
    const int*   ei    = (const int*)d_in[2];
    const int*   batch = (const int*)d_in[3];
    const float* eps   = (const float*)d_in[4];
    const float* W1    = (const float*)d_in[5];
    const float* b1    = (const float*)d_in[6];
    const float* Wmu   = (const float*)d_in[7];
    const float* bmu   = (const float*)d_in[8];
    const float* Wlv   = (const float*)d_in[9];
    const float* blv   = (const float*)d_in[10];
    const float* wp    = (const float*)d_in[11];
    float* ws = (float*)d_ws;
    int*  iws = (int*)d_ws;
    float* out = (float*)d_out;

    hipMemsetAsync(iws + OFF_CNT, 0, 65536 * 4, stream);
    hipMemsetAsync(iws + OFF_CUR, 0, 65536 * 4, stream);

    k_count<<<NE / 256, 256, 0, stream>>>(ei, iws + OFF_CNT);
    k_scan<<<1, 1024, 0, stream>>>(iws + OFF_CNT, iws + OFF_ROWPTR, ws + OFF_DINV);
    k_scatter<<<NE / 256, 256, 0, stream>>>(ei, iws + OFF_ROWPTR, iws + OFF_CUR, ws + OFF_DINV,
                                            iws + OFF_ESRC, ws + OFF_ENORM);
    k_wnorm<<<1, 128, 0, stream>>>(wp, ws + OFF_INVWN);

    k_gemm<0><<<NN / 128, 256, 0, stream>>>(x_raw, pe, W1, nullptr, ws + OFF_T0);
    k_agg1<<<NN / 4, 256, 0, stream>>>(ws + OFF_T0, iws + OFF_ROWPTR, iws + OFF_ESRC, ws + OFF_ENORM,
                                       ws + OFF_DINV, b1, ws + OFF_H);
    k_gemm<1><<<NN / 128, 256, 0, stream>>>(ws + OFF_H, nullptr, Wmu, Wlv, ws + OFF_T0);
    k_agg2<<<NN / 4, 256, 0, stream>>>(ws + OFF_T0, iws + OFF_ROWPTR, iws + OFF_ESRC, ws + OFF_ENORM,
                                       ws + OFF_DINV, bmu, blv, eps, wp, ws + OFF_INVWN,
                                       ws + OFF_MU, ws + OFF_LV, ws + OFF_SCORE);
    k_topk<<<NGRAPH, 512, 0, stream>>>(ws + OFF_SCORE, batch, iws + OFF_KEEP, out);
    k_gather<<<NGRAPH * KPER, 128, 0, stream>>>(iws + OFF_KEEP, ws + OFF_MU, ws + OFF_LV, eps,
                                                ws + OFF_SCORE, out);
}

// Round 3
// 841.242 us; speedup vs baseline: 1.9031x; 1.1773x over previous
//
#include <hip/hip_runtime.h>
#include <math.h>

#define NN      65536
#define NE      1048576
#define NPER    1024
#define NGRAPH  64
#define KPER    512
#define IND     192
#define PED     64
#define HID     256
#define LAT     128

// workspace offsets (4-byte elements)
#define OFF_CNT     0u          // 65536 int
#define OFF_ROWPTR  65536u      // 65537 int
#define OFF_CUR     132096u     // 65536 int
#define OFF_DINV    198656u     // 65536 f
#define OFF_ESRC    264192u     // 1048576 int
#define OFF_ENORM   1312768u    // 1048576 f
#define OFF_INVWN   2361344u    // 1 f
#define OFF_KEEP    2361360u    // 32768 int
#define OFF_SCORE   2395136u    // 65536 f
#define OFF_T0      2460672u    // 16777216 f  (t0, reused as t1)
#define OFF_H       19237888u   // 16777216 f  (h, reused as mu|lv)
#define OFF_MU      19237888u
#define OFF_LV      27626496u

// d_out offsets (floats)
#define OUT_MU      4194304
#define OUT_LV      8388608
#define OUT_BATCH   12582912
#define OUT_PERM    12615680

__global__ __launch_bounds__(256) void k_count(const int* __restrict__ ei, int* __restrict__ cnt) {
    int e = blockIdx.x * 256 + threadIdx.x;
    atomicAdd(&cnt[ei[NE + e]], 1);
}

__global__ __launch_bounds__(1024) void k_scan(const int* __restrict__ cnt, int* __restrict__ rp,
                                               float* __restrict__ dinv) {
    __shared__ int part[1024];
    const int t = threadIdx.x;
    const int base = t * 64;
    int s = 0;
    for (int i = 0; i < 64; ++i) s += cnt[base + i];
    part[t] = s;
    __syncthreads();
    for (int d = 1; d < 1024; d <<= 1) {
        int v = (t >= d) ? part[t - d] : 0;
        __syncthreads();
        part[t] += v;
        __syncthreads();
    }
    int run = part[t] - s;   // exclusive prefix over threads
    for (int i = 0; i < 64; ++i) {
        int c = cnt[base + i];
        rp[base + i] = run;
        run += c;
        dinv[base + i] = 1.0f / sqrtf((float)(c + 1));  // +1 self loop
    }
    if (t == 1023) rp[NN] = run;
}

__global__ __launch_bounds__(256) void k_scatter(const int* __restrict__ ei, const int* __restrict__ rp,
                                                 int* __restrict__ cur, const float* __restrict__ dinv,
                                                 int* __restrict__ esrc, float* __restrict__ enorm) {
    int e = blockIdx.x * 256 + threadIdx.x;
    int s = ei[e];
    int d = ei[NE + e];
    int pos = rp[d] + atomicAdd(&cur[d], 1);
    esrc[pos] = s;
    enorm[pos] = dinv[s] * dinv[d];
}

__global__ __launch_bounds__(128) void k_wnorm(const float* __restrict__ wp, float* __restrict__ invwn) {
    __shared__ float red[128];
    int t = threadIdx.x;
    float v = wp[t];
    red[t] = v * v;
    __syncthreads();
    for (int s = 64; s > 0; s >>= 1) {
        if (t < s) red[t] += red[t + s];
        __syncthreads();
    }
    if (t == 0) invwn[0] = 1.0f / sqrtf(red[0]);
}

#define FMA4(d, a, b) \
    d.x = fmaf(a, b.x, d.x); d.y = fmaf(a, b.y, d.y); \
    d.z = fmaf(a, b.z, d.z); d.w = fmaf(a, b.w, d.w)

// Register-blocked SGEMM: C[N,256] = A[N,256] @ B[256,256]
// Block tile M=128 x N=256 (A fetched exactly once), BK=16, 16 stages.
// 512 threads; micro-tile 8 rows x 8 cols (cols tx*4+{0,128}) -> acc = 64 VGPRs, NO SPILL.
// A in LDS transposed (pad 132), B row-major; register prefetch across stages.
// MODE 0: A = [x_raw(192) | pe(64)], B = W1[256x256]
// MODE 1: A = h[N,256],  B = [Wmu(256x128) | Wlv(256x128)] col-concat
template <int MODE>
__global__ __launch_bounds__(512, 4) void k_gemm(const float* __restrict__ A0, const float* __restrict__ A1,
                                                 const float* __restrict__ B0, const float* __restrict__ B1,
                                                 float* __restrict__ C) {
    __shared__ float Alds[16 * 132];
    __shared__ float Blds[16 * 256];
    const int tid = threadIdx.x;
    const int tx = tid & 31;     // col group: cols tx*4 + {0,128}
    const int ty = tid >> 5;     // row group: rows ty*8 .. ty*8+7
    const int Rbase = blockIdx.x * 128;

    // staging indices
    const int rowA = tid >> 2;        // 0..127
    const int c4   = (tid & 3) * 4;   // 0,4,8,12
    const int krB  = tid >> 5;        // 0..15
    const int cbB  = (tid & 31) * 4;  // 0..124

    float4 pa, pb0, pb1;

    auto loadA = [&](int s, float4& v) {
        const float* p; int ld, ko;
        if (MODE == 0) {
            if (s < 12) { p = A0; ld = IND; ko = s * 16; }
            else        { p = A1; ld = PED; ko = s * 16 - IND; }
        } else { p = A0; ld = 256; ko = s * 16; }
        v = *(const float4*)(p + (size_t)(Rbase + rowA) * ld + ko + c4);
    };
    auto loadB = [&](int s, float4& b0, float4& b1) {
        const int k = s * 16 + krB;
        if (MODE == 0) {
            const float* p = B0 + (size_t)k * 256;
            b0 = *(const float4*)(p + cbB);
            b1 = *(const float4*)(p + cbB + 128);
        } else {
            b0 = *(const float4*)(B0 + (size_t)k * 128 + cbB);
            b1 = *(const float4*)(B1 + (size_t)k * 128 + cbB);
        }
    };

    float4 acc[8][2];
#pragma unroll
    for (int r = 0; r < 8; ++r) {
        acc[r][0] = make_float4(0.f, 0.f, 0.f, 0.f);
        acc[r][1] = make_float4(0.f, 0.f, 0.f, 0.f);
    }

    loadA(0, pa);
    loadB(0, pb0, pb1);

    for (int s = 0; s < 16; ++s) {
#pragma unroll
        for (int j = 0; j < 4; ++j)
            Alds[(c4 + j) * 132 + rowA] = ((const float*)&pa)[j];
        *(float4*)&Blds[krB * 256 + cbB]       = pb0;
        *(float4*)&Blds[krB * 256 + cbB + 128] = pb1;
        __syncthreads();
        if (s < 15) { loadA(s + 1, pa); loadB(s + 1, pb0, pb1); }
#pragma unroll
        for (int k = 0; k < 16; ++k) {
            const float4 a0 = *(const float4*)&Alds[k * 132 + ty * 8];
            const float4 a1 = *(const float4*)&Alds[k * 132 + ty * 8 + 4];
            const float4 b0 = *(const float4*)&Blds[k * 256 + tx * 4];
            const float4 b1 = *(const float4*)&Blds[k * 256 + tx * 4 + 128];
            const float ar[8] = {a0.x, a0.y, a0.z, a0.w, a1.x, a1.y, a1.z, a1.w};
#pragma unroll
            for (int r = 0; r < 8; ++r) {
                FMA4(acc[r][0], ar[r], b0);
                FMA4(acc[r][1], ar[r], b1);
            }
        }
        __syncthreads();
    }

#pragma unroll
    for (int r = 0; r < 8; ++r) {
        const int row = Rbase + ty * 8 + r;
        *(float4*)(C + (size_t)row * 256 + tx * 4)       = acc[r][0];
        *(float4*)(C + (size_t)row * 256 + tx * 4 + 128) = acc[r][1];
    }
}

// aggregation 1: h = relu(sum_{in-edges} norm * t0[src] + dinv^2 * t0[node] + b1)
// wave per node; edges processed in coalesced 64-wide chunks broadcast via shfl.
__global__ __launch_bounds__(256) void k_agg1(const float* __restrict__ t0, const int* __restrict__ rp,
                                              const int* __restrict__ esrc, const float* __restrict__ enorm,
                                              const float* __restrict__ dinv, const float* __restrict__ bias,
                                              float* __restrict__ hout) {
    const int wv = threadIdx.x >> 6, lane = threadIdx.x & 63;
    const int node = blockIdx.x * 4 + wv;
    const int c0 = lane * 4;
    const float di = dinv[node];
    float4 acc = *(const float4*)(t0 + (size_t)node * 256 + c0);
    const float sw = di * di;
    acc.x *= sw; acc.y *= sw; acc.z *= sw; acc.w *= sw;
    const int beg = rp[node], end = rp[node + 1];
    for (int base = beg; base < end; base += 64) {
        const int m = min(64, end - base);
        int sv = 0; float nv = 0.0f;
        if (lane < m) { sv = esrc[base + lane]; nv = enorm[base + lane]; }
        float4 vj = *(const float4*)(t0 + (size_t)__shfl(sv, 0, 64) * 256 + c0);
        for (int j = 0; j < m; ++j) {
            const float wgt = __shfl(nv, j, 64);
            float4 vnext;
            if (j + 1 < m) vnext = *(const float4*)(t0 + (size_t)__shfl(sv, j + 1, 64) * 256 + c0);
            acc.x = fmaf(wgt, vj.x, acc.x);
            acc.y = fmaf(wgt, vj.y, acc.y);
            acc.z = fmaf(wgt, vj.z, acc.z);
            acc.w = fmaf(wgt, vj.w, acc.w);
            vj = vnext;
        }
    }
    const float4 bb = *(const float4*)(bias + c0);
    float4 r;
    r.x = fmaxf(acc.x + bb.x, 0.0f);
    r.y = fmaxf(acc.y + bb.y, 0.0f);
    r.z = fmaxf(acc.z + bb.z, 0.0f);
    r.w = fmaxf(acc.w + bb.w, 0.0f);
    *(float4*)(hout + (size_t)node * 256 + c0) = r;
}

// aggregation 2: t1 cols 0..127 -> mu, 128..255 -> lv; also z & score
__global__ __launch_bounds__(256) void k_agg2(const float* __restrict__ t1, const int* __restrict__ rp,
                                              const int* __restrict__ esrc, const float* __restrict__ enorm,
                                              const float* __restrict__ dinv, const float* __restrict__ bmu,
                                              const float* __restrict__ blv, const float* __restrict__ eps,
                                              const float* __restrict__ wp, const float* __restrict__ invwn,
                                              float* __restrict__ mu, float* __restrict__ lv,
                                              float* __restrict__ score) {
    const int wv = threadIdx.x >> 6, lane = threadIdx.x & 63;
    const int node = blockIdx.x * 4 + wv;
    const int c0 = lane * 4;
    const float di = dinv[node];
    float4 acc = *(const float4*)(t1 + (size_t)node * 256 + c0);
    const float sw = di * di;
    acc.x *= sw; acc.y *= sw; acc.z *= sw; acc.w *= sw;
    const int beg = rp[node], end = rp[node + 1];
    for (int base = beg; base < end; base += 64) {
        const int m = min(64, end - base);
        int sv = 0; float nv = 0.0f;
        if (lane < m) { sv = esrc[base + lane]; nv = enorm[base + lane]; }
        float4 vj = *(const float4*)(t1 + (size_t)__shfl(sv, 0, 64) * 256 + c0);
        for (int j = 0; j < m; ++j) {
            const float wgt = __shfl(nv, j, 64);
            float4 vnext;
            if (j + 1 < m) vnext = *(const float4*)(t1 + (size_t)__shfl(sv, j + 1, 64) * 256 + c0);
            acc.x = fmaf(wgt, vj.x, acc.x);
            acc.y = fmaf(wgt, vj.y, acc.y);
            acc.z = fmaf(wgt, vj.z, acc.z);
            acc.w = fmaf(wgt, vj.w, acc.w);
            vj = vnext;
        }
    }
    const int cb = (lane & 31) * 4;
    const float* bias = (lane < 32) ? bmu : blv;
    const float4 bb = *(const float4*)(bias + cb);
    acc.x += bb.x; acc.y += bb.y; acc.z += bb.z; acc.w += bb.w;
    if (lane < 32) *(float4*)(mu + (size_t)node * 128 + cb) = acc;
    else           *(float4*)(lv + (size_t)node * 128 + cb) = acc;
    // z = mu + eps*exp(0.5*lv); partial dot with w_pool (lanes 0..31 hold mu cols)
    float4 l4;
    l4.x = __shfl(acc.x, lane | 32, 64);
    l4.y = __shfl(acc.y, lane | 32, 64);
    l4.z = __shfl(acc.z, lane | 32, 64);
    l4.w = __shfl(acc.w, lane | 32, 64);
    float partial = 0.0f;
    if (lane < 32) {
        const float4 e4 = *(const float4*)(eps + (size_t)node * 128 + cb);
        const float4 w4 = *(const float4*)(wp + cb);
        float zx = fmaf(e4.x, expf(0.5f * l4.x), acc.x);
        float zy = fmaf(e4.y, expf(0.5f * l4.y), acc.y);
        float zz = fmaf(e4.z, expf(0.5f * l4.z), acc.z);
        float zw = fmaf(e4.w, expf(0.5f * l4.w), acc.w);
        partial = zx * w4.x + zy * w4.y + zz * w4.z + zw * w4.w;
    }
    for (int off = 16; off > 0; off >>= 1) partial += __shfl_xor(partial, off, 64);
    if (lane == 0) score[node] = tanhf(partial * invwn[0]);
}

// per-graph bitonic top-k: sort 1024 (score desc, idx asc), emit top 512
__global__ __launch_bounds__(512) void k_topk(const float* __restrict__ score, const int* __restrict__ batch,
                                              int* __restrict__ keep, float* __restrict__ out) {
    __shared__ float sk[1024];
    __shared__ int si[1024];
    const int g = blockIdx.x, t = threadIdx.x;
    for (int i = t; i < 1024; i += 512) {
        sk[i] = score[g * 1024 + i];
        si[i] = i;
    }
    __syncthreads();
    for (int k = 2; k <= 1024; k <<= 1) {
        for (int j = k >> 1; j > 0; j >>= 1) {
            for (int base = 0; base < 1024; base += 512) {
                int i = base + t;
                int ixj = i ^ j;
                if (ixj > i) {
                    float a = sk[i], b = sk[ixj];
                    int ia = si[i], ib = si[ixj];
                    bool before = (a > b) || (a == b && ia < ib);
                    bool up = ((i & k) == 0);
                    bool sw = up ? (!before) : before;
                    if (sw) {
                        sk[i] = b; si[i] = ib;
                        sk[ixj] = a; si[ixj] = ia;
                    }
                }
            }
            __syncthreads();
        }
    }
    if (t < KPER) {
        int node = g * 1024 + si[t];
        keep[g * KPER + t] = node;
        out[OUT_BATCH + g * KPER + t] = (float)batch[node];
        out[OUT_PERM + g * KPER + t] = (float)node;
    }
}

__global__ __launch_bounds__(128) void k_gather(const int* __restrict__ keep, const float* __restrict__ mu,
                                                const float* __restrict__ lv, const float* __restrict__ eps,
                                                const float* __restrict__ score, float* __restrict__ out) {
    const int kidx = blockIdx.x;
    const int c = threadIdx.x;
    const int node = keep[kidx];
    const float m = mu[(size_t)node * 128 + c];
    const float l = lv[(size_t)node * 128 + c];
    const float e = eps[(size_t)node * 128 + c];
    const float z = fmaf(e, expf(0.5f * l), m);
    const float s = score[node];
    out[(size_t)kidx * 128 + c] = z * s;
    out[OUT_MU + (size_t)kidx * 128 + c] = m;
    out[OUT_LV + (size_t)kidx * 128 + c] = l;
}

extern "C" void kernel_launch(void* const* d_in, const int* in_sizes, int n_in,
                              void* d_out, int out_size, void* d_ws, size_t ws_size,
                              hipStream_t stream) {
    (void)in_sizes; (void)n_in; (void)out_size; (void)ws_size;
    const float* x_raw = (const float*)d_in[0];
    const float* pe    = (const float*)d_in[1];
    const int*   ei    = (const int*)d_in[2];
    const int*   batch = (const int*)d_in[3];
    const float* eps   = (const float*)d_in[4];
    const float* W1    = (const float*)d_in[5];
    const float* b1    = (const float*)d_in[6];
    const float* Wmu   = (const float*)d_in[7];
    const float* bmu   = (const float*)d_in[8];
    const float* Wlv   = (const float*)d_in[9];
    const float* blv   = (const float*)d_in[10];
    const float* wp    = (const float*)d_in[11];
    float* ws = (float*)d_ws;
    int*  iws = (int*)d_ws;
    float* out = (float*)d_out;

    hipMemsetAsync(iws + OFF_CNT, 0, 65536 * 4, stream);
    hipMemsetAsync(iws + OFF_CUR, 0, 65536 * 4, stream);

    k_count<<<NE / 256, 256, 0, stream>>>(ei, iws + OFF_CNT);
    k_scan<<<1, 1024, 0, stream>>>(iws + OFF_CNT, iws + OFF_ROWPTR, ws + OFF_DINV);
    k_scatter<<<NE / 256, 256, 0, stream>>>(ei, iws + OFF_ROWPTR, iws + OFF_CUR, ws + OFF_DINV,
                                            iws + OFF_ESRC, ws + OFF_ENORM);
    k_wnorm<<<1, 128, 0, stream>>>(wp, ws + OFF_INVWN);

    k_gemm<0><<<NN / 128, 512, 0, stream>>>(x_raw, pe, W1, nullptr, ws + OFF_T0);
    k_agg1<<<NN / 4, 256, 0, stream>>>(ws + OFF_T0, iws + OFF_ROWPTR, iws + OFF_ESRC, ws + OFF_ENORM,
                                       ws + OFF_DINV, b1, ws + OFF_H);
    k_gemm<1><<<NN / 128, 512, 0, stream>>>(ws + OFF_H, nullptr, Wmu, Wlv, ws + OFF_T0);
    k_agg2<<<NN / 4, 256, 0, stream>>>(ws + OFF_T0, iws + OFF_ROWPTR, iws + OFF_ESRC, ws + OFF_ENORM,
                                       ws + OFF_DINV, bmu, blv, eps, wp, ws + OFF_INVWN,
                                       ws + OFF_MU, ws + OFF_LV, ws + OFF_SCORE);
    k_topk<<<NGRAPH, 512, 0, stream>>>(ws + OFF_SCORE, batch, iws + OFF_KEEP, out);
    k_gather<<<NGRAPH * KPER, 128, 0, stream>>>(iws + OFF_KEEP, ws + OFF_MU, ws + OFF_LV, eps,
                                                ws + OFF_SCORE, out);
}

// Round 4
// 573.582 us; speedup vs baseline: 2.7912x; 1.4666x over previous
//
#include <hip/hip_runtime.h>
#include <math.h>

#define NN      65536
#define NE      1048576
#define NPER    1024
#define NGRAPH  64
#define KPER    512
#define IND     192
#define PED     64
#define HID     256
#define LAT     128

// workspace offsets (in 4-byte slots)
#define OFF_CNT     0u          // 65536 int
#define OFF_ROWPTR  65536u      // 65537 int
#define OFF_CUR     132096u     // 65536 int
#define OFF_DINV    198656u     // 65536 f
#define OFF_ESRC    264192u     // 1048576 int
#define OFF_ENORM   1312768u    // 1048576 f
#define OFF_INVWN   2361344u    // 1 f
#define OFF_KEEP    2361360u    // 32768 int
#define OFF_SCORE   2395136u    // 65536 f
#define OFF_WT1     2460672u    // 65536 bf16 (32768 slots): W1^T
#define OFF_WT2     2493440u    // 65536 bf16: [Wmu|Wlv]^T
#define OFF_T0B     2526208u    // 16777216 bf16 (8388608 slots): t0, reused as t1
#define OFF_HB      10914816u   // 16777216 bf16: h
#define OFF_MU      10914816u   // 8388608 f  (overlays h, h dead after gemm2)
#define OFF_LV      19303424u   // 8388608 f

// d_out offsets (floats)
#define OUT_MU      4194304
#define OUT_LV      8388608
#define OUT_BATCH   12582912
#define OUT_PERM    12615680

typedef __attribute__((ext_vector_type(8))) short short8;
typedef __attribute__((ext_vector_type(4))) float floatx4;

__device__ __forceinline__ unsigned short f2bf(float f) {
    unsigned int u = __float_as_uint(f);
    u += 0x7FFFu + ((u >> 16) & 1u);
    return (unsigned short)(u >> 16);
}
__device__ __forceinline__ float bf2f(unsigned short u) {
    return __uint_as_float(((unsigned int)u) << 16);
}
__device__ __forceinline__ float4 b2f4(ushort4 u) {
    float4 r;
    r.x = bf2f(u.x); r.y = bf2f(u.y); r.z = bf2f(u.z); r.w = bf2f(u.w);
    return r;
}

__global__ __launch_bounds__(256) void k_count(const int* __restrict__ ei, int* __restrict__ cnt) {
    int e = blockIdx.x * 256 + threadIdx.x;
    atomicAdd(&cnt[ei[NE + e]], 1);
}

__global__ __launch_bounds__(1024) void k_scan(const int* __restrict__ cnt, int* __restrict__ rp,
                                               float* __restrict__ dinv) {
    __shared__ int part[1024];
    const int t = threadIdx.x;
    const int base = t * 64;
    int s = 0;
    for (int i = 0; i < 64; ++i) s += cnt[base + i];
    part[t] = s;
    __syncthreads();
    for (int d = 1; d < 1024; d <<= 1) {
        int v = (t >= d) ? part[t - d] : 0;
        __syncthreads();
        part[t] += v;
        __syncthreads();
    }
    int run = part[t] - s;
    for (int i = 0; i < 64; ++i) {
        int c = cnt[base + i];
        rp[base + i] = run;
        run += c;
        dinv[base + i] = 1.0f / sqrtf((float)(c + 1));
    }
    if (t == 1023) rp[NN] = run;
}

__global__ __launch_bounds__(256) void k_scatter(const int* __restrict__ ei, const int* __restrict__ rp,
                                                 int* __restrict__ cur, const float* __restrict__ dinv,
                                                 int* __restrict__ esrc, float* __restrict__ enorm) {
    int e = blockIdx.x * 256 + threadIdx.x;
    int s = ei[e];
    int d = ei[NE + e];
    int pos = rp[d] + atomicAdd(&cur[d], 1);
    esrc[pos] = s;
    enorm[pos] = dinv[s] * dinv[d];
}

__global__ __launch_bounds__(128) void k_wnorm(const float* __restrict__ wp, float* __restrict__ invwn) {
    __shared__ float red[128];
    int t = threadIdx.x;
    float v = wp[t];
    red[t] = v * v;
    __syncthreads();
    for (int s = 64; s > 0; s >>= 1) {
        if (t < s) red[t] += red[t + s];
        __syncthreads();
    }
    if (t == 0) invwn[0] = 1.0f / sqrtf(red[0]);
}

// transpose + bf16-convert weights: wt1[n][k] = W1[k][n]; wt2[n][k] = (Wmu|Wlv)[k][n]
__global__ __launch_bounds__(256) void k_prepw(const float* __restrict__ W1, const float* __restrict__ Wmu,
                                               const float* __restrict__ Wlv, unsigned short* __restrict__ wt1,
                                               unsigned short* __restrict__ wt2) {
    const int n = blockIdx.x, k = threadIdx.x;
    wt1[n * 256 + k] = f2bf(W1[k * 256 + n]);
    wt2[n * 256 + k] = f2bf((n < 128) ? Wmu[k * 128 + n] : Wlv[k * 128 + (n - 128)]);
}

// MFMA bf16 GEMM: C[N,256](bf16) = A[N,256] @ B[256,256]
// block: 256 thr = 4 waves, tile M=128 x N=256, K-step 32 (8 steps).
// LDS holds A/B in fragment order: [tile][quad][lane16] 16B units -> conflict-free ds_read_b128.
// MODE 0: A = [x_raw(192,f32) | pe(64,f32)], B = wt1 (W1^T bf16)
// MODE 1: A = h (bf16),                      B = wt2 ([Wmu|Wlv]^T bf16)
template <int MODE>
__global__ __launch_bounds__(256, 2) void k_gemm(const float* __restrict__ A0f, const float* __restrict__ A1f,
                                                 const unsigned short* __restrict__ Ab,
                                                 const unsigned short* __restrict__ Wt,
                                                 unsigned short* __restrict__ Cb) {
    __shared__ unsigned short lds[12288];   // A: 8 tiles*64u*8 = 4096, B: 16*64*8 = 8192
    const int tid = threadIdx.x;
    const int w = __builtin_amdgcn_readfirstlane(tid >> 6);
    const int lane = tid & 63;
    const int l = lane & 15, q = lane >> 4;
    const int Rbase = blockIdx.x * 128;

    const int rs = tid >> 1;       // 0..127 (staging row)
    const int ch = tid & 1;        // k-chunk of 16
    const int stile = rs >> 4, sl = rs & 15, q0 = ch * 2;
    const int uA = (stile * 4 + q0) * 16 + sl;      // A unit idx

    floatx4 acc[16][2];
#pragma unroll
    for (int nt = 0; nt < 16; ++nt) {
        acc[nt][0] = (floatx4)0.0f;
        acc[nt][1] = (floatx4)0.0f;
    }

    for (int ks = 0; ks < 8; ++ks) {
        // ---- stage A (one 32B chunk per thread) ----
        unsigned short abuf[16];
        if (MODE == 0) {
            const float* p; int ld, col;
            const int k = ks * 32 + ch * 16;
            if (ks < 6) { p = A0f; ld = IND; col = k; }
            else        { p = A1f; ld = PED; col = k - IND; }
            const float* src = p + (size_t)(Rbase + rs) * ld + col;
#pragma unroll
            for (int j = 0; j < 16; j += 4) {
                const float4 t = *(const float4*)(src + j);
                abuf[j] = f2bf(t.x); abuf[j + 1] = f2bf(t.y);
                abuf[j + 2] = f2bf(t.z); abuf[j + 3] = f2bf(t.w);
            }
        } else {
            const unsigned short* src = Ab + (size_t)(Rbase + rs) * 256 + ks * 32 + ch * 16;
            *(uint4*)&abuf[0] = ((const uint4*)src)[0];
            *(uint4*)&abuf[8] = ((const uint4*)src)[1];
        }
        *(uint4*)&lds[uA * 8]        = *(uint4*)&abuf[0];
        *(uint4*)&lds[(uA + 16) * 8] = *(uint4*)&abuf[8];
        // ---- stage B (two 32B chunks per thread) ----
#pragma unroll
        for (int rep = 0; rep < 2; ++rep) {
            const int n = rep * 128 + rs;
            const unsigned short* src = Wt + (size_t)n * 256 + ks * 32 + ch * 16;
            const uint4 w0 = ((const uint4*)src)[0];
            const uint4 w1 = ((const uint4*)src)[1];
            const int uB = ((n >> 4) * 4 + q0) * 16 + (n & 15);
            *(uint4*)&lds[4096 + uB * 8]        = w0;
            *(uint4*)&lds[4096 + (uB + 16) * 8] = w1;
        }
        __syncthreads();
        // ---- compute ----
        const short8 a0 = *(const short8*)&lds[(((2 * w) * 4 + q) * 16 + l) * 8];
        const short8 a1 = *(const short8*)&lds[(((2 * w + 1) * 4 + q) * 16 + l) * 8];
#pragma unroll
        for (int nt = 0; nt < 16; ++nt) {
            const short8 b = *(const short8*)&lds[4096 + ((nt * 4 + q) * 16 + l) * 8];
            acc[nt][0] = __builtin_amdgcn_mfma_f32_16x16x32_bf16(a0, b, acc[nt][0], 0, 0, 0);
            acc[nt][1] = __builtin_amdgcn_mfma_f32_16x16x32_bf16(a1, b, acc[nt][1], 0, 0, 0);
        }
        __syncthreads();
    }

    // ---- store C (bf16) ----
#pragma unroll
    for (int m = 0; m < 2; ++m) {
        const int mt = 2 * w + m;
#pragma unroll
        for (int nt = 0; nt < 16; ++nt) {
            const floatx4 v = acc[nt][m];
            size_t base = (size_t)(Rbase + mt * 16 + q * 4) * 256 + nt * 16 + l;
            Cb[base]       = f2bf(v[0]);
            Cb[base + 256] = f2bf(v[1]);
            Cb[base + 512] = f2bf(v[2]);
            Cb[base + 768] = f2bf(v[3]);
        }
    }
}

// aggregation 1: h = relu(sum norm*t0[src] + dinv^2*t0[node] + b1), bf16 table in/out
__global__ __launch_bounds__(256) void k_agg1(const unsigned short* __restrict__ t0b, const int* __restrict__ rp,
                                              const int* __restrict__ esrc, const float* __restrict__ enorm,
                                              const float* __restrict__ dinv, const float* __restrict__ bias,
                                              unsigned short* __restrict__ hb) {
    const int wv = threadIdx.x >> 6, lane = threadIdx.x & 63;
    const int node = blockIdx.x * 4 + wv;
    const int c0 = lane * 4;
    const float di = dinv[node];
    float4 acc = b2f4(*(const ushort4*)(t0b + ((size_t)node << 8) + c0));
    const float sw = di * di;
    acc.x *= sw; acc.y *= sw; acc.z *= sw; acc.w *= sw;
    const int beg = rp[node], end = rp[node + 1];
    for (int base = beg; base < end; base += 64) {
        const int m = min(64, end - base);
        int sv = 0; float nv = 0.0f;
        if (lane < m) { sv = esrc[base + lane]; nv = enorm[base + lane]; }
        ushort4 vj = *(const ushort4*)(t0b + ((size_t)__shfl(sv, 0, 64) << 8) + c0);
        for (int j = 0; j < m; ++j) {
            const float wgt = __shfl(nv, j, 64);
            ushort4 vnext;
            if (j + 1 < m) vnext = *(const ushort4*)(t0b + ((size_t)__shfl(sv, j + 1, 64) << 8) + c0);
            const float4 v = b2f4(vj);
            acc.x = fmaf(wgt, v.x, acc.x);
            acc.y = fmaf(wgt, v.y, acc.y);
            acc.z = fmaf(wgt, v.z, acc.z);
            acc.w = fmaf(wgt, v.w, acc.w);
            vj = vnext;
        }
    }
    const float4 bb = *(const float4*)(bias + c0);
    ushort4 r;
    r.x = f2bf(fmaxf(acc.x + bb.x, 0.0f));
    r.y = f2bf(fmaxf(acc.y + bb.y, 0.0f));
    r.z = f2bf(fmaxf(acc.z + bb.z, 0.0f));
    r.w = f2bf(fmaxf(acc.w + bb.w, 0.0f));
    *(ushort4*)(hb + ((size_t)node << 8) + c0) = r;
}

// aggregation 2: t1(bf16) cols 0..127 -> mu, 128..255 -> lv (fp32 out); also z & score
__global__ __launch_bounds__(256) void k_agg2(const unsigned short* __restrict__ t1b, const int* __restrict__ rp,
                                              const int* __restrict__ esrc, const float* __restrict__ enorm,
                                              const float* __restrict__ dinv, const float* __restrict__ bmu,
                                              const float* __restrict__ blv, const float* __restrict__ eps,
                                              const float* __restrict__ wp, const float* __restrict__ invwn,
                                              float* __restrict__ mu, float* __restrict__ lv,
                                              float* __restrict__ score) {
    const int wv = threadIdx.x >> 6, lane = threadIdx.x & 63;
    const int node = blockIdx.x * 4 + wv;
    const int c0 = lane * 4;
    const float di = dinv[node];
    float4 acc = b2f4(*(const ushort4*)(t1b + ((size_t)node << 8) + c0));
    const float sw = di * di;
    acc.x *= sw; acc.y *= sw; acc.z *= sw; acc.w *= sw;
    const int beg = rp[node], end = rp[node + 1];
    for (int base = beg; base < end; base += 64) {
        const int m = min(64, end - base);
        int sv = 0; float nv = 0.0f;
        if (lane < m) { sv = esrc[base + lane]; nv = enorm[base + lane]; }
        ushort4 vj = *(const ushort4*)(t1b + ((size_t)__shfl(sv, 0, 64) << 8) + c0);
        for (int j = 0; j < m; ++j) {
            const float wgt = __shfl(nv, j, 64);
            ushort4 vnext;
            if (j + 1 < m) vnext = *(const ushort4*)(t1b + ((size_t)__shfl(sv, j + 1, 64) << 8) + c0);
            const float4 v = b2f4(vj);
            acc.x = fmaf(wgt, v.x, acc.x);
            acc.y = fmaf(wgt, v.y, acc.y);
            acc.z = fmaf(wgt, v.z, acc.z);
            acc.w = fmaf(wgt, v.w, acc.w);
            vj = vnext;
        }
    }
    const int cb = (lane & 31) * 4;
    const float* bias = (lane < 32) ? bmu : blv;
    const float4 bb = *(const float4*)(bias + cb);
    acc.x += bb.x; acc.y += bb.y; acc.z += bb.z; acc.w += bb.w;
    if (lane < 32) *(float4*)(mu + (size_t)node * 128 + cb) = acc;
    else           *(float4*)(lv + (size_t)node * 128 + cb) = acc;
    float4 l4;
    l4.x = __shfl(acc.x, lane | 32, 64);
    l4.y = __shfl(acc.y, lane | 32, 64);
    l4.z = __shfl(acc.z, lane | 32, 64);
    l4.w = __shfl(acc.w, lane | 32, 64);
    float partial = 0.0f;
    if (lane < 32) {
        const float4 e4 = *(const float4*)(eps + (size_t)node * 128 + cb);
        const float4 w4 = *(const float4*)(wp + cb);
        float zx = fmaf(e4.x, expf(0.5f * l4.x), acc.x);
        float zy = fmaf(e4.y, expf(0.5f * l4.y), acc.y);
        float zz = fmaf(e4.z, expf(0.5f * l4.z), acc.z);
        float zw = fmaf(e4.w, expf(0.5f * l4.w), acc.w);
        partial = zx * w4.x + zy * w4.y + zz * w4.z + zw * w4.w;
    }
    for (int off = 16; off > 0; off >>= 1) partial += __shfl_xor(partial, off, 64);
    if (lane == 0) score[node] = tanhf(partial * invwn[0]);
}

// per-graph bitonic top-k: sort 1024 (score desc, idx asc), emit top 512
__global__ __launch_bounds__(512) void k_topk(const float* __restrict__ score, const int* __restrict__ batch,
                                              int* __restrict__ keep, float* __restrict__ out) {
    __shared__ float sk[1024];
    __shared__ int si[1024];
    const int g = blockIdx.x, t = threadIdx.x;
    for (int i = t; i < 1024; i += 512) {
        sk[i] = score[g * 1024 + i];
        si[i] = i;
    }
    __syncthreads();
    for (int k = 2; k <= 1024; k <<= 1) {
        for (int j = k >> 1; j > 0; j >>= 1) {
            for (int base = 0; base < 1024; base += 512) {
                int i = base + t;
                int ixj = i ^ j;
                if (ixj > i) {
                    float a = sk[i], b = sk[ixj];
                    int ia = si[i], ib = si[ixj];
                    bool before = (a > b) || (a == b && ia < ib);
                    bool up = ((i & k) == 0);
                    bool sw = up ? (!before) : before;
                    if (sw) {
                        sk[i] = b; si[i] = ib;
                        sk[ixj] = a; si[ixj] = ia;
                    }
                }
            }
            __syncthreads();
        }
    }
    if (t < KPER) {
        int node = g * 1024 + si[t];
        keep[g * KPER + t] = node;
        out[OUT_BATCH + g * KPER + t] = (float)batch[node];
        out[OUT_PERM + g * KPER + t] = (float)node;
    }
}

__global__ __launch_bounds__(128) void k_gather(const int* __restrict__ keep, const float* __restrict__ mu,
                                                const float* __restrict__ lv, const float* __restrict__ eps,
                                                const float* __restrict__ score, float* __restrict__ out) {
    const int kidx = blockIdx.x;
    const int c = threadIdx.x;
    const int node = keep[kidx];
    const float m = mu[(size_t)node * 128 + c];
    const float l = lv[(size_t)node * 128 + c];
    const float e = eps[(size_t)node * 128 + c];
    const float z = fmaf(e, expf(0.5f * l), m);
    const float s = score[node];
    out[(size_t)kidx * 128 + c] = z * s;
    out[OUT_MU + (size_t)kidx * 128 + c] = m;
    out[OUT_LV + (size_t)kidx * 128 + c] = l;
}

extern "C" void kernel_launch(void* const* d_in, const int* in_sizes, int n_in,
                              void* d_out, int out_size, void* d_ws, size_t ws_size,
                              hipStream_t stream) {
    (void)in_sizes; (void)n_in; (void)out_size; (void)ws_size;
    const float* x_raw = (const float*)d_in[0];
    const float* pe    = (const float*)d_in[1];
    const int*   ei    = (const int*)d_in[2];
    const int*   batch = (const int*)d_in[3];
    const float* eps   = (const float*)d_in[4];
    const float* W1    = (const float*)d_in[5];
    const float* b1    = (const float*)d_in[6];
    const float* Wmu   = (const float*)d_in[7];
    const float* bmu   = (const float*)d_in[8];
    const float* Wlv   = (const float*)d_in[9];
    const float* blv   = (const float*)d_in[10];
    const float* wp    = (const float*)d_in[11];
    float* ws = (float*)d_ws;
    int*  iws = (int*)d_ws;
    unsigned short* wt1 = (unsigned short*)(ws + OFF_WT1);
    unsigned short* wt2 = (unsigned short*)(ws + OFF_WT2);
    unsigned short* t0b = (unsigned short*)(ws + OFF_T0B);
    unsigned short* hb  = (unsigned short*)(ws + OFF_HB);
    float* out = (float*)d_out;

    hipMemsetAsync(iws + OFF_CNT, 0, 65536 * 4, stream);
    hipMemsetAsync(iws + OFF_CUR, 0, 65536 * 4, stream);

    k_count<<<NE / 256, 256, 0, stream>>>(ei, iws + OFF_CNT);
    k_scan<<<1, 1024, 0, stream>>>(iws + OFF_CNT, iws + OFF_ROWPTR, ws + OFF_DINV);
    k_scatter<<<NE / 256, 256, 0, stream>>>(ei, iws + OFF_ROWPTR, iws + OFF_CUR, ws + OFF_DINV,
                                            iws + OFF_ESRC, ws + OFF_ENORM);
    k_wnorm<<<1, 128, 0, stream>>>(wp, ws + OFF_INVWN);
    k_prepw<<<256, 256, 0, stream>>>(W1, Wmu, Wlv, wt1, wt2);

    k_gemm<0><<<NN / 128, 256, 0, stream>>>(x_raw, pe, nullptr, wt1, t0b);
    k_agg1<<<NN / 4, 256, 0, stream>>>(t0b, iws + OFF_ROWPTR, iws + OFF_ESRC, ws + OFF_ENORM,
                                       ws + OFF_DINV, b1, hb);
    k_gemm<1><<<NN / 128, 256, 0, stream>>>(nullptr, nullptr, hb, wt2, t0b);
    k_agg2<<<NN / 4, 256, 0, stream>>>(t0b, iws + OFF_ROWPTR, iws + OFF_ESRC, ws + OFF_ENORM,
                                       ws + OFF_DINV, bmu, blv, eps, wp, ws + OFF_INVWN,
                                       ws + OFF_MU, ws + OFF_LV, ws + OFF_SCORE);
    k_topk<<<NGRAPH, 512, 0, stream>>>(ws + OFF_SCORE, batch, iws + OFF_KEEP, out);
    k_gather<<<NGRAPH * KPER, 128, 0, stream>>>(iws + OFF_KEEP, ws + OFF_MU, ws + OFF_LV, eps,
                                                ws + OFF_SCORE, out);
}

// Round 5
// 538.564 us; speedup vs baseline: 2.9727x; 1.0650x over previous
//
#include <hip/hip_runtime.h>
#include <hip/hip_fp16.h>
#include <math.h>

#define NN      65536
#define NE      1048576
#define NPER    1024
#define NGRAPH  64
#define KPER    512
#define IND     192
#define PED     64
#define HID     256
#define LAT     128

// workspace offsets (in 4-byte slots)
#define OFF_CNT     0u          // 65536 int
#define OFF_ROWPTR  65536u      // 65537 int
#define OFF_CUR     132096u     // 65536 int
#define OFF_DINV    198656u     // 65536 f
#define OFF_ESRC    264192u     // 1048576 int
#define OFF_ENORM   1312768u    // 1048576 f
#define OFF_INVWN   2361344u    // 1 f
#define OFF_KEEP    2361360u    // 32768 int
#define OFF_SCORE   2395136u    // 65536 f
#define OFF_WT1     2460672u    // 65536 bf16 (32768 slots): W1^T
#define OFF_WT2     2493440u    // 65536 bf16: [Wmu|Wlv]^T
#define OFF_T0B     2526208u    // 16777216 fp8 (4194304 slots): t0, reused as t1
#define OFF_HB      6720512u    // 16777216 fp8: h
#define OFF_MUB     10914816u   // 8388608 bf16 (4194304 slots)
#define OFF_LVB     15109120u   // 8388608 bf16 (4194304 slots)

// d_out offsets (floats)
#define OUT_MU      4194304
#define OUT_LV      8388608
#define OUT_BATCH   12582912
#define OUT_PERM    12615680

typedef __attribute__((ext_vector_type(8))) short short8;
typedef __attribute__((ext_vector_type(4))) float floatx4;

__device__ __forceinline__ unsigned short f2bf(float f) {
    unsigned int u = __float_as_uint(f);
    u += 0x7FFFu + ((u >> 16) & 1u);
    return (unsigned short)(u >> 16);
}
__device__ __forceinline__ float bf2f(unsigned short u) {
    return __uint_as_float(((unsigned int)u) << 16);
}
// fp8 e5m2 = top byte of fp16 (round-nearest-even on truncate)
__device__ __forceinline__ unsigned char f2e5(float f) {
    unsigned short u = __half_as_ushort(__float2half(f));
    u += (unsigned short)(0x7Fu + ((u >> 8) & 1u));
    return (unsigned char)(u >> 8);
}
__device__ __forceinline__ float e52f(unsigned char c) {
    return __half2float(__ushort_as_half((unsigned short)((unsigned short)c << 8)));
}
__device__ __forceinline__ float4 e52f4(uchar4 u) {
    float4 r;
    r.x = e52f(u.x); r.y = e52f(u.y); r.z = e52f(u.z); r.w = e52f(u.w);
    return r;
}

__global__ __launch_bounds__(256) void k_count(const int* __restrict__ ei, int* __restrict__ cnt) {
    int e = blockIdx.x * 256 + threadIdx.x;
    atomicAdd(&cnt[ei[NE + e]], 1);
}

__global__ __launch_bounds__(1024) void k_scan(const int* __restrict__ cnt, int* __restrict__ rp,
                                               float* __restrict__ dinv) {
    __shared__ int part[1024];
    const int t = threadIdx.x;
    const int base = t * 64;
    int loc[64];
#pragma unroll
    for (int i = 0; i < 64; i += 4)
        *(int4*)&loc[i] = *(const int4*)(cnt + base + i);
    int s = 0;
#pragma unroll
    for (int i = 0; i < 64; ++i) s += loc[i];
    part[t] = s;
    __syncthreads();
    for (int d = 1; d < 1024; d <<= 1) {
        int v = (t >= d) ? part[t - d] : 0;
        __syncthreads();
        part[t] += v;
        __syncthreads();
    }
    int run = part[t] - s;
    int rpo[64];
    float dv[64];
#pragma unroll
    for (int i = 0; i < 64; ++i) {
        rpo[i] = run;
        run += loc[i];
        dv[i] = 1.0f / sqrtf((float)(loc[i] + 1));
    }
#pragma unroll
    for (int i = 0; i < 64; i += 4) {
        *(int4*)(rp + base + i) = *(int4*)&rpo[i];
        *(float4*)(dinv + base + i) = *(float4*)&dv[i];
    }
    if (t == 1023) rp[NN] = run;
}

__global__ __launch_bounds__(256) void k_scatter(const int* __restrict__ ei, const int* __restrict__ rp,
                                                 int* __restrict__ cur, const float* __restrict__ dinv,
                                                 int* __restrict__ esrc, float* __restrict__ enorm) {
    int e = blockIdx.x * 256 + threadIdx.x;
    int s = ei[e];
    int d = ei[NE + e];
    int pos = rp[d] + atomicAdd(&cur[d], 1);
    esrc[pos] = s;
    enorm[pos] = dinv[s] * dinv[d];
}

__global__ __launch_bounds__(128) void k_wnorm(const float* __restrict__ wp, float* __restrict__ invwn) {
    __shared__ float red[128];
    int t = threadIdx.x;
    float v = wp[t];
    red[t] = v * v;
    __syncthreads();
    for (int s = 64; s > 0; s >>= 1) {
        if (t < s) red[t] += red[t + s];
        __syncthreads();
    }
    if (t == 0) invwn[0] = 1.0f / sqrtf(red[0]);
}

// transpose + bf16-convert weights: wt1[n][k] = W1[k][n]; wt2[n][k] = (Wmu|Wlv)[k][n]
__global__ __launch_bounds__(256) void k_prepw(const float* __restrict__ W1, const float* __restrict__ Wmu,
                                               const float* __restrict__ Wlv, unsigned short* __restrict__ wt1,
                                               unsigned short* __restrict__ wt2) {
    const int n = blockIdx.x, k = threadIdx.x;
    wt1[n * 256 + k] = f2bf(W1[k * 256 + n]);
    wt2[n * 256 + k] = f2bf((n < 128) ? Wmu[k * 128 + n] : Wlv[k * 128 + (n - 128)]);
}

// MFMA bf16 GEMM: C[N,256](fp8 e5m2) = A[N,256] @ B[256,256]
// block: 256 thr = 4 waves, tile M=128 x N=256, K-step 32 (8 steps).
// LDS holds A/B bf16 in fragment order -> conflict-free ds_read_b128.
// MODE 0: A = [x_raw(192,f32) | pe(64,f32)], B = wt1 (W1^T bf16)
// MODE 1: A = h (fp8),                       B = wt2 ([Wmu|Wlv]^T bf16)
template <int MODE>
__global__ __launch_bounds__(256, 2) void k_gemm(const float* __restrict__ A0f, const float* __restrict__ A1f,
                                                 const unsigned char* __restrict__ Ab,
                                                 const unsigned short* __restrict__ Wt,
                                                 unsigned char* __restrict__ Cb) {
    __shared__ unsigned short lds[12288];   // A: 8 tiles*64u*8 = 4096, B: 16*64*8 = 8192
    const int tid = threadIdx.x;
    const int w = __builtin_amdgcn_readfirstlane(tid >> 6);
    const int lane = tid & 63;
    const int l = lane & 15, q = lane >> 4;
    const int Rbase = blockIdx.x * 128;

    const int rs = tid >> 1;       // 0..127 (staging row)
    const int ch = tid & 1;        // k-chunk of 16
    const int stile = rs >> 4, sl = rs & 15, q0 = ch * 2;
    const int uA = (stile * 4 + q0) * 16 + sl;      // A unit idx

    floatx4 acc[16][2];
#pragma unroll
    for (int nt = 0; nt < 16; ++nt) {
        acc[nt][0] = (floatx4)0.0f;
        acc[nt][1] = (floatx4)0.0f;
    }

    for (int ks = 0; ks < 8; ++ks) {
        // ---- stage A (16 values per thread) ----
        unsigned short abuf[16];
        if (MODE == 0) {
            const float* p; int ld, col;
            const int k = ks * 32 + ch * 16;
            if (ks < 6) { p = A0f; ld = IND; col = k; }
            else        { p = A1f; ld = PED; col = k - IND; }
            const float* src = p + (size_t)(Rbase + rs) * ld + col;
#pragma unroll
            for (int j = 0; j < 16; j += 4) {
                const float4 t = *(const float4*)(src + j);
                abuf[j] = f2bf(t.x); abuf[j + 1] = f2bf(t.y);
                abuf[j + 2] = f2bf(t.z); abuf[j + 3] = f2bf(t.w);
            }
        } else {
            const unsigned char* src = Ab + (size_t)(Rbase + rs) * 256 + ks * 32 + ch * 16;
            uint4 pk = *(const uint4*)src;
#pragma unroll
            for (int j = 0; j < 16; ++j) {
                unsigned char c = ((const unsigned char*)&pk)[j];
                abuf[j] = (unsigned short)(__float_as_uint(e52f(c)) >> 16);
            }
        }
        *(uint4*)&lds[uA * 8]        = *(uint4*)&abuf[0];
        *(uint4*)&lds[(uA + 16) * 8] = *(uint4*)&abuf[8];
        // ---- stage B (two 32B chunks per thread) ----
#pragma unroll
        for (int rep = 0; rep < 2; ++rep) {
            const int n = rep * 128 + rs;
            const unsigned short* src = Wt + (size_t)n * 256 + ks * 32 + ch * 16;
            const uint4 w0 = ((const uint4*)src)[0];
            const uint4 w1 = ((const uint4*)src)[1];
            const int uB = ((n >> 4) * 4 + q0) * 16 + (n & 15);
            *(uint4*)&lds[4096 + uB * 8]        = w0;
            *(uint4*)&lds[4096 + (uB + 16) * 8] = w1;
        }
        __syncthreads();
        // ---- compute ----
        const short8 a0 = *(const short8*)&lds[(((2 * w) * 4 + q) * 16 + l) * 8];
        const short8 a1 = *(const short8*)&lds[(((2 * w + 1) * 4 + q) * 16 + l) * 8];
#pragma unroll
        for (int nt = 0; nt < 16; ++nt) {
            const short8 b = *(const short8*)&lds[4096 + ((nt * 4 + q) * 16 + l) * 8];
            acc[nt][0] = __builtin_amdgcn_mfma_f32_16x16x32_bf16(a0, b, acc[nt][0], 0, 0, 0);
            acc[nt][1] = __builtin_amdgcn_mfma_f32_16x16x32_bf16(a1, b, acc[nt][1], 0, 0, 0);
        }
        __syncthreads();
    }

    // ---- store C (fp8) ----
#pragma unroll
    for (int m = 0; m < 2; ++m) {
        const int mt = 2 * w + m;
#pragma unroll
        for (int nt = 0; nt < 16; ++nt) {
            const floatx4 v = acc[nt][m];
            size_t base = (size_t)(Rbase + mt * 16 + q * 4) * 256 + nt * 16 + l;
            Cb[base]       = f2e5(v[0]);
            Cb[base + 256] = f2e5(v[1]);
            Cb[base + 512] = f2e5(v[2]);
            Cb[base + 768] = f2e5(v[3]);
        }
    }
}

// aggregation 1: h = relu(sum norm*t0[src] + dinv^2*t0[node] + b1), fp8 table in/out
__global__ __launch_bounds__(256) void k_agg1(const unsigned char* __restrict__ t0b, const int* __restrict__ rp,
                                              const int* __restrict__ esrc, const float* __restrict__ enorm,
                                              const float* __restrict__ dinv, const float* __restrict__ bias,
                                              unsigned char* __restrict__ hb) {
    const int wv = threadIdx.x >> 6, lane = threadIdx.x & 63;
    const int node = blockIdx.x * 4 + wv;
    const int c0 = lane * 4;
    const float di = dinv[node];
    float4 acc = e52f4(*(const uchar4*)(t0b + ((size_t)node << 8) + c0));
    const float sw = di * di;
    acc.x *= sw; acc.y *= sw; acc.z *= sw; acc.w *= sw;
    const int beg = rp[node], end = rp[node + 1];
    for (int base = beg; base < end; base += 64) {
        const int m = min(64, end - base);
        int sv = 0; float nv = 0.0f;
        if (lane < m) { sv = esrc[base + lane]; nv = enorm[base + lane]; }
        uchar4 vj = *(const uchar4*)(t0b + ((size_t)__shfl(sv, 0, 64) << 8) + c0);
        for (int j = 0; j < m; ++j) {
            const float wgt = __shfl(nv, j, 64);
            uchar4 vnext;
            if (j + 1 < m) vnext = *(const uchar4*)(t0b + ((size_t)__shfl(sv, j + 1, 64) << 8) + c0);
            const float4 v = e52f4(vj);
            acc.x = fmaf(wgt, v.x, acc.x);
            acc.y = fmaf(wgt, v.y, acc.y);
            acc.z = fmaf(wgt, v.z, acc.z);
            acc.w = fmaf(wgt, v.w, acc.w);
            vj = vnext;
        }
    }
    const float4 bb = *(const float4*)(bias + c0);
    uchar4 r;
    r.x = f2e5(fmaxf(acc.x + bb.x, 0.0f));
    r.y = f2e5(fmaxf(acc.y + bb.y, 0.0f));
    r.z = f2e5(fmaxf(acc.z + bb.z, 0.0f));
    r.w = f2e5(fmaxf(acc.w + bb.w, 0.0f));
    *(uchar4*)(hb + ((size_t)node << 8) + c0) = r;
}

// aggregation 2: t1(fp8) cols 0..127 -> mu, 128..255 -> lv (bf16 out); also z & score
__global__ __launch_bounds__(256) void k_agg2(const unsigned char* __restrict__ t1b, const int* __restrict__ rp,
                                              const int* __restrict__ esrc, const float* __restrict__ enorm,
                                              const float* __restrict__ dinv, const float* __restrict__ bmu,
                                              const float* __restrict__ blv, const float* __restrict__ eps,
                                              const float* __restrict__ wp, const float* __restrict__ invwn,
                                              unsigned short* __restrict__ mub, unsigned short* __restrict__ lvb,
                                              float* __restrict__ score) {
    const int wv = threadIdx.x >> 6, lane = threadIdx.x & 63;
    const int node = blockIdx.x * 4 + wv;
    const int c0 = lane * 4;
    const float di = dinv[node];
    float4 acc = e52f4(*(const uchar4*)(t1b + ((size_t)node << 8) + c0));
    const float sw = di * di;
    acc.x *= sw; acc.y *= sw; acc.z *= sw; acc.w *= sw;
    const int beg = rp[node], end = rp[node + 1];
    for (int base = beg; base < end; base += 64) {
        const int m = min(64, end - base);
        int sv = 0; float nv = 0.0f;
        if (lane < m) { sv = esrc[base + lane]; nv = enorm[base + lane]; }
        uchar4 vj = *(const uchar4*)(t1b + ((size_t)__shfl(sv, 0, 64) << 8) + c0);
        for (int j = 0; j < m; ++j) {
            const float wgt = __shfl(nv, j, 64);
            uchar4 vnext;
            if (j + 1 < m) vnext = *(const uchar4*)(t1b + ((size_t)__shfl(sv, j + 1, 64) << 8) + c0);
            const float4 v = e52f4(vj);
            acc.x = fmaf(wgt, v.x, acc.x);
            acc.y = fmaf(wgt, v.y, acc.y);
            acc.z = fmaf(wgt, v.z, acc.z);
            acc.w = fmaf(wgt, v.w, acc.w);
            vj = vnext;
        }
    }
    const int cb = (lane & 31) * 4;
    const float* bias = (lane < 32) ? bmu : blv;
    const float4 bb = *(const float4*)(bias + cb);
    acc.x += bb.x; acc.y += bb.y; acc.z += bb.z; acc.w += bb.w;
    unsigned short* dst = (lane < 32) ? mub : lvb;
    ushort4 st;
    st.x = f2bf(acc.x); st.y = f2bf(acc.y); st.z = f2bf(acc.z); st.w = f2bf(acc.w);
    *(ushort4*)(dst + (size_t)node * 128 + cb) = st;
    float4 l4;
    l4.x = __shfl(acc.x, lane | 32, 64);
    l4.y = __shfl(acc.y, lane | 32, 64);
    l4.z = __shfl(acc.z, lane | 32, 64);
    l4.w = __shfl(acc.w, lane | 32, 64);
    float partial = 0.0f;
    if (lane < 32) {
        const float4 e4 = *(const float4*)(eps + (size_t)node * 128 + cb);
        const float4 w4 = *(const float4*)(wp + cb);
        float zx = fmaf(e4.x, expf(0.5f * l4.x), acc.x);
        float zy = fmaf(e4.y, expf(0.5f * l4.y), acc.y);
        float zz = fmaf(e4.z, expf(0.5f * l4.z), acc.z);
        float zw = fmaf(e4.w, expf(0.5f * l4.w), acc.w);
        partial = zx * w4.x + zy * w4.y + zz * w4.z + zw * w4.w;
    }
    for (int off = 16; off > 0; off >>= 1) partial += __shfl_xor(partial, off, 64);
    if (lane == 0) score[node] = tanhf(partial * invwn[0]);
}

// per-graph bitonic top-k: sort 1024 (score desc, idx asc), emit top 512
__global__ __launch_bounds__(512) void k_topk(const float* __restrict__ score, const int* __restrict__ batch,
                                              int* __restrict__ keep, float* __restrict__ out) {
    __shared__ float sk[1024];
    __shared__ int si[1024];
    const int g = blockIdx.x, t = threadIdx.x;
    for (int i = t; i < 1024; i += 512) {
        sk[i] = score[g * 1024 + i];
        si[i] = i;
    }
    __syncthreads();
    for (int k = 2; k <= 1024; k <<= 1) {
        for (int j = k >> 1; j > 0; j >>= 1) {
            for (int base = 0; base < 1024; base += 512) {
                int i = base + t;
                int ixj = i ^ j;
                if (ixj > i) {
                    float a = sk[i], b = sk[ixj];
                    int ia = si[i], ib = si[ixj];
                    bool before = (a > b) || (a == b && ia < ib);
                    bool up = ((i & k) == 0);
                    bool sw = up ? (!before) : before;
                    if (sw) {
                        sk[i] = b; si[i] = ib;
                        sk[ixj] = a; si[ixj] = ia;
                    }
                }
            }
            __syncthreads();
        }
    }
    if (t < KPER) {
        int node = g * 1024 + si[t];
        keep[g * KPER + t] = node;
        out[OUT_BATCH + g * KPER + t] = (float)batch[node];
        out[OUT_PERM + g * KPER + t] = (float)node;
    }
}

__global__ __launch_bounds__(128) void k_gather(const int* __restrict__ keep,
                                                const unsigned short* __restrict__ mub,
                                                const unsigned short* __restrict__ lvb,
                                                const float* __restrict__ eps,
                                                const float* __restrict__ score, float* __restrict__ out) {
    const int kidx = blockIdx.x;
    const int c = threadIdx.x;
    const int node = keep[kidx];
    const float m = bf2f(mub[(size_t)node * 128 + c]);
    const float l = bf2f(lvb[(size_t)node * 128 + c]);
    const float e = eps[(size_t)node * 128 + c];
    const float z = fmaf(e, expf(0.5f * l), m);
    const float s = score[node];
    out[(size_t)kidx * 128 + c] = z * s;
    out[OUT_MU + (size_t)kidx * 128 + c] = m;
    out[OUT_LV + (size_t)kidx * 128 + c] = l;
}

extern "C" void kernel_launch(void* const* d_in, const int* in_sizes, int n_in,
                              void* d_out, int out_size, void* d_ws, size_t ws_size,
                              hipStream_t stream) {
    (void)in_sizes; (void)n_in; (void)out_size; (void)ws_size;
    const float* x_raw = (const float*)d_in[0];
    const float* pe    = (const float*)d_in[1];
    const int*   ei    = (const int*)d_in[2];
    const int*   batch = (const int*)d_in[3];
    const float* eps   = (const float*)d_in[4];
    const float* W1    = (const float*)d_in[5];
    const float* b1    = (const float*)d_in[6];
    const float* Wmu   = (const float*)d_in[7];
    const float* bmu   = (const float*)d_in[8];
    const float* Wlv   = (const float*)d_in[9];
    const float* blv   = (const float*)d_in[10];
    const float* wp    = (const float*)d_in[11];
    float* ws = (float*)d_ws;
    int*  iws = (int*)d_ws;
    unsigned short* wt1 = (unsigned short*)(ws + OFF_WT1);
    unsigned short* wt2 = (unsigned short*)(ws + OFF_WT2);
    unsigned char*  t0b = (unsigned char*)(ws + OFF_T0B);
    unsigned char*  hb  = (unsigned char*)(ws + OFF_HB);
    unsigned short* mub = (unsigned short*)(ws + OFF_MUB);
    unsigned short* lvb = (unsigned short*)(ws + OFF_LVB);
    float* out = (float*)d_out;

    hipMemsetAsync(iws + OFF_CNT, 0, 65536 * 4, stream);
    hipMemsetAsync(iws + OFF_CUR, 0, 65536 * 4, stream);

    k_count<<<NE / 256, 256, 0, stream>>>(ei, iws + OFF_CNT);
    k_scan<<<1, 1024, 0, stream>>>(iws + OFF_CNT, iws + OFF_ROWPTR, ws + OFF_DINV);
    k_scatter<<<NE / 256, 256, 0, stream>>>(ei, iws + OFF_ROWPTR, iws + OFF_CUR, ws + OFF_DINV,
                                            iws + OFF_ESRC, ws + OFF_ENORM);
    k_wnorm<<<1, 128, 0, stream>>>(wp, ws + OFF_INVWN);
    k_prepw<<<256, 256, 0, stream>>>(W1, Wmu, Wlv, wt1, wt2);

    k_gemm<0><<<NN / 128, 256, 0, stream>>>(x_raw, pe, nullptr, wt1, t0b);
    k_agg1<<<NN / 4, 256, 0, stream>>>(t0b, iws + OFF_ROWPTR, iws + OFF_ESRC, ws + OFF_ENORM,
                                       ws + OFF_DINV, b1, hb);
    k_gemm<1><<<NN / 128, 256, 0, stream>>>(nullptr, nullptr, hb, wt2, t0b);
    k_agg2<<<NN / 4, 256, 0, stream>>>(t0b, iws + OFF_ROWPTR, iws + OFF_ESRC, ws + OFF_ENORM,
                                       ws + OFF_DINV, bmu, blv, eps, wp, ws + OFF_INVWN,
                                       mub, lvb, ws + OFF_SCORE);
    k_topk<<<NGRAPH, 512, 0, stream>>>(ws + OFF_SCORE, batch, iws + OFF_KEEP, out);
    k_gather<<<NGRAPH * KPER, 128, 0, stream>>>(iws + OFF_KEEP, mub, lvb, eps,
                                                ws + OFF_SCORE, out);
}